// Round 19
// baseline (761.852 us; speedup 1.0000x reference)
//
#include <hip/hip_runtime.h>
#include <hip/hip_bf16.h>

// ELMo 2-layer biLSTM, B=64 T=256 U=256. Persistent RNN, data-tagged sync.
//  R19 = R14 protocol, SPLIT-PHASE TICK: each ring's store lands mid-tick and
//  propagates under the OTHER layer's half-tick of compute.
//   L0 phase: poll h0 -> stage -> U0@h0 -> zpart -> combine L0 -> store h0.
//   L1 phase: poll h1 -> stage -> W1@h0 + U1@h1 -> zpart -> combine L1 ->
//             ea refill -> store h1.
//  Polls: R14-exact single-phase full-window (32B/thread/ring, 8 tags).
//  Wave-uniform ledgers: tlay0 tick-start VMCNT(0), pend rides h1-poll;
//  tlay1 tick-start VMCNT(1) (leaves own h1 ring store), pend rides h0-poll;
//  poll iter1 VMCNT(1) only when a store rides (else VMCNT(0)); miss VMCNT(0).
//  h1 ring valid from tick0 (zeros, tag1) -> no doH1 guards. zpart single 8KB
//  (BAR-separated reuse). 4 barriers/tick.
//  LEDGER RULES: full-window single-phase poll (R7/8/13); sc0 sc1 only (R12);
//  coalesced ring stores (R11); 16-WG clusters (R15); nothing young+slow
//  older than poll loads (R16); no serial cross-lane hops (R17).

#define TT 256
#define TM 255
#define NU 256
#define NG 1024
#define BB 64

typedef __attribute__((ext_vector_type(8))) short short8;
typedef __attribute__((ext_vector_type(4))) float f32x4;
typedef __attribute__((ext_vector_type(4))) unsigned int u32x4;

__device__ __forceinline__ unsigned short f2bf(float v) {
  unsigned int x = __float_as_uint(v);
  return (unsigned short)((x + 0x7FFFu + ((x >> 16) & 1u)) >> 16);
}
__device__ __forceinline__ float sigm(float x) { return 1.f / (1.f + __expf(-x)); }
__device__ __forceinline__ float tanhp(float x) {
  x = fminf(fmaxf(x, -15.f), 15.f);
  float e = __expf(-2.f * x);
  return (1.f - e) / (1.f + e);
}
#define VMCNT(n) asm volatile("s_waitcnt vmcnt(" #n ")" ::: "memory")
#define LGKM0() asm volatile("s_waitcnt lgkmcnt(0)" ::: "memory")
#define SCHEDBAR() __builtin_amdgcn_sched_barrier(0)
#define BAR() __builtin_amdgcn_s_barrier()

#define LLC_LOAD16(dst, ptr) \
  asm volatile("global_load_dwordx4 %0, %1, off sc0 sc1" : "=&v"(dst) : "v"(ptr) : "memory")
#define CACH_LOAD16(dst, ptr) \
  asm volatile("global_load_dwordx4 %0, %1, off" : "=&v"(dst) : "v"(ptr) : "memory")
#define STORE4(ptr, val) \
  asm volatile("global_store_dword %0, %1, off" :: "v"(ptr), "v"(val) : "memory")

__global__ void embed_kernel(const int* __restrict__ seqs, const float* __restrict__ E,
                             unsigned short* __restrict__ embb, float* __restrict__ out) {
  int b = blockIdx.x, t = blockIdx.y, d = threadIdx.x;
  int s = seqs[b * TT + t];
  float v = E[(size_t)s * NU + d];
  embb[((size_t)(b * TT + t)) * NU + d] = f2bf(v);
  if (t < TM) out[(((size_t)(0 * BB + b)) * TM + t) * NU + d] = v;
  if (t >= 1) out[(((size_t)(3 * BB + b)) * TM + (t - 1)) * NU + d] = v;
}

__device__ __forceinline__ bool tags8(const u32x4& x, const u32x4& y, unsigned tg) {
  return (x[0] >> 16) == tg && (x[1] >> 16) == tg && (x[2] >> 16) == tg &&
         (x[3] >> 16) == tg && (y[0] >> 16) == tg && (y[1] >> 16) == tg &&
         (y[2] >> 16) == tg && (y[3] >> 16) == tg;
}

__launch_bounds__(512, 1)
__global__ void lstm_kernel(const int* __restrict__ seqs,
                            const float* __restrict__ Wf, const float* __restrict__ Uf,
                            const float* __restrict__ bf,
                            const float* __restrict__ Wb, const float* __restrict__ Ub,
                            const float* __restrict__ bb,
                            const unsigned short* __restrict__ embb,
                            unsigned int* __restrict__ Hbuf, float* __restrict__ out) {
  extern __shared__ char smem[];
  float* zpart = (float*)smem;                    // [4][2][16][16] f32 = 8KB (shared L0/L1)
  char* hlb0 = smem + 8192;                       // 8KB swizzled h0 tile
  char* hlb1 = smem + 16384;                      // 8KB swizzled h1 tile
  unsigned char* mskl = (unsigned char*)(smem + 24576);  // [64][256] = 16KB

  const int tid = threadIdx.x;
  const int blk = blockIdx.x;
  const int cluster = blk & 7, slice = blk >> 3;  // cluster -> same XCD (perf only)
  const int dir = cluster >> 2, rg = cluster & 3;
  const int ubase = slice << 4;
  const int wave = tid >> 6, g = wave & 3, kh = wave >> 2;
  const int lane = tid & 63, q = lane >> 4, n15 = lane & 15;
  const int tlay = tid >> 8, ct = tid & 255, crow = ct >> 4, cn = ct & 15;
  const int brow = rg * 16 + crow;

  const float* W0 = dir ? Wb : Wf;
  const float* U0 = dir ? Ub : Uf;
  const float* b0p = dir ? bb : bf;
  const float* mats[4] = {W0, U0, W0 + NU * NG, U0 + NU * NG};

  // ---- weights -> VGPRs: wreg[m*4+kb][j] = mat[kh*128+kb*32+q*8+j][g*256+ubase+n15]
  short8 wreg[16];
  {
    const int col = g * 256 + ubase + n15;
    #pragma unroll
    for (int m = 0; m < 4; m++) {
      #pragma unroll
      for (int kb = 0; kb < 4; kb++) {
        short8 t;
        #pragma unroll
        for (int j = 0; j < 8; j++)
          t[j] = (short)f2bf(mats[m][(size_t)(kh * 128 + kb * 32 + q * 8 + j) * NG + col]);
        wreg[m * 4 + kb] = t;
      }
    }
  }

  // ---- mask table (LDS)
  for (int i = tid; i < 64 * 256; i += 512) {
    int row = i >> 8, s = i & 255;
    mskl[i] = (s < TM) ? (seqs[row * TT + (dir ? TM - s : s)] != 0) : 0;
  }

  float bi[4];
  {
    const float* bp = tlay ? (b0p + NG) : b0p;
    #pragma unroll
    for (int gg = 0; gg < 4; gg++) bi[gg] = bp[(gg << 8) + ubase + cn];
  }
  float cst = 0.f, hv = 0.f;  // tlay0: (c0,h0) state; tlay1: (c1,h1) state

  __syncthreads();

  const int wsw = (tid * 16) ^ (((tid >> 5) & 7) << 4);
  const int fb = n15 * 512 + kh * 256;
  const int fx = (n15 & 7) << 4;
  const int zwr = (g << 9) + (kh << 8) + n15;

  // ring word slot: [lay][parity][cluster][4096]
  unsigned int* hst = Hbuf + ((size_t)(tlay * 16 + cluster)) * 4096 + crow * 256 + ubase + cn;
  float* dump = (float*)((char*)Hbuf + 524288) + (blk * 512 + tid);

  const float* pendA = dump;
  float pendV = 0.f;

  short8 ea[4];  // emb A-frags for the CURRENT tick (prefetched previous tick)

  // ================= tick 0: emb-only, L0 combine; h1 ring seeded (zeros) ====
  {
    int tx = dir ? TM : 0;
    const unsigned short* ep =
        embb + ((size_t)((rg * 16 + n15) * TT + tx)) * NU + kh * 128 + q * 8;
    f32x4 acc0 = {0.f, 0.f, 0.f, 0.f};
    #pragma unroll
    for (int kb = 0; kb < 4; kb++) {
      short8 a = *(const short8*)(ep + kb * 32);
      acc0 = __builtin_amdgcn_mfma_f32_16x16x32_bf16(a, wreg[kb], acc0, 0, 0, 0);
    }
    #pragma unroll
    for (int j = 0; j < 4; j++) zpart[zwr + (((q << 2) + j) << 4)] = acc0[j];
    LGKM0(); SCHEDBAR(); BAR();
    if (tlay == 0) {
      float z[4];
      #pragma unroll
      for (int gg = 0; gg < 4; gg++)
        z[gg] = zpart[(gg * 2) * 256 + crow * 16 + cn] +
                zpart[(gg * 2 + 1) * 256 + crow * 16 + cn] + bi[gg];
      float cnw = sigm(z[1]) * cst + sigm(z[0]) * tanhp(z[2]);
      float hnw = sigm(z[3]) * tanhp(cnw);
      if (mskl[brow * 256 + 0]) { cst = cnw; hv = hnw; }
      int tout = dir ? TM - 1 : 0;
      STORE4(out + (((size_t)((1 + dir * 3) * BB + brow)) * TM + tout) * NU + ubase + cn, hv);
    }
    // ea prefetch for tick 1 (before ring stores)
    {
      int tx1 = dir ? TM - 1 : 1;
      const unsigned short* e1 =
          embb + ((size_t)((rg * 16 + n15) * TT + tx1)) * NU + kh * 128 + q * 8;
      #pragma unroll
      for (int kb = 0; kb < 4; kb++) CACH_LOAD16(ea[kb], e1 + kb * 32);
    }
    SCHEDBAR();
    // ring store tag1 parity0: tlay0 -> h0[0]; tlay1 -> h1 zeros (hv=0)
    __hip_atomic_store(hst, (1u << 16) | (unsigned)f2bf(hv),
                       __ATOMIC_RELAXED, __HIP_MEMORY_SCOPE_AGENT);
  }

  // ================= ticks 1..255 (split-phase) =================
  for (int tau = 1; tau < 256; ++tau) {
    const bool doL0 = (tau < TM);
    const unsigned tg = (unsigned)tau;
    const int p = (tau + 1) & 1;

    // tick start: tlay0 drains all (pend+ea acked long ago); tlay1 drains ea,
    // leaves own h1 ring store pending.
    if (tlay == 0) { VMCNT(0); } else { VMCNT(1); }
    SCHEDBAR();

    f32x4 acc0 = {0.f, 0.f, 0.f, 0.f}, acc1 = {0.f, 0.f, 0.f, 0.f};
    if (doL0) {  // pre-poll emb MFMAs
      #pragma unroll
      for (int kb = 0; kb < 4; kb++)
        acc0 = __builtin_amdgcn_mfma_f32_16x16x32_bf16(ea[kb], wreg[kb], acc0, 0, 0, 0);
      SCHEDBAR();
    }

    // ======== L0 PHASE ========
    // ---- h0 poll (full 32B/thread, single-phase; tlay1's pend rides iter1)
    const unsigned int* c0a = Hbuf + ((size_t)(p * 8 + cluster)) * 4096 + tid * 8;
    const unsigned int* c0b = c0a + 4;
    u32x4 a0 = {0, 0, 0, 0}, a1 = {0, 0, 0, 0};
    {
      bool first = true;
      int miss = 0;
      for (;;) {
        LLC_LOAD16(a0, c0a);
        LLC_LOAD16(a1, c0b);
        if (first) {
          first = false;
          if (tlay == 1) { STORE4(pendA, pendV); VMCNT(1); } else { VMCNT(0); }
        } else {
          VMCNT(0);
        }
        SCHEDBAR();
        if (__all(tags8(a0, a1, tg))) break;
        if (++miss > 2) __builtin_amdgcn_s_sleep(1);
      }
    }
    // stage h0
    u32x4 s0;
    s0[0] = (a0[0] & 0xFFFFu) | (a0[1] << 16);
    s0[1] = (a0[2] & 0xFFFFu) | (a0[3] << 16);
    s0[2] = (a1[0] & 0xFFFFu) | (a1[1] << 16);
    s0[3] = (a1[2] & 0xFFFFu) | (a1[3] << 16);
    *(u32x4*)(hlb0 + wsw) = s0;
    LGKM0(); SCHEDBAR(); BAR();

    // U0 @ h0 (shortest possible L0 critical segment)
    if (doL0) {
      #pragma unroll
      for (int kb = 0; kb < 4; kb++) {
        short8 h0f = *(const short8*)(hlb0 + ((fb + kb * 64 + q * 16) ^ fx));
        acc0 = __builtin_amdgcn_mfma_f32_16x16x32_bf16(h0f, wreg[4 + kb], acc0, 0, 0, 0);
      }
      #pragma unroll
      for (int j = 0; j < 4; j++) zpart[zwr + (((q << 2) + j) << 4)] = acc0[j];
    }
    LGKM0(); SCHEDBAR(); BAR();

    // combine L0 + EARLY h0 ring store (mid-tick: propagates under L1 phase)
    if (tlay == 0 && doL0) {
      float z[4];
      #pragma unroll
      for (int gg = 0; gg < 4; gg++)
        z[gg] = zpart[(gg * 2) * 256 + crow * 16 + cn] +
                zpart[(gg * 2 + 1) * 256 + crow * 16 + cn] + bi[gg];
      float cnw = sigm(z[1]) * cst + sigm(z[0]) * tanhp(z[2]);
      float hnw = sigm(z[3]) * tanhp(cnw);
      if (mskl[brow * 256 + tau]) { cst = cnw; hv = hnw; }
      __hip_atomic_store(hst + (size_t)(tau & 1) * 32768,
                         ((unsigned)(tau + 1) << 16) | (unsigned)f2bf(hv),
                         __ATOMIC_RELAXED, __HIP_MEMORY_SCOPE_AGENT);
      int tout = dir ? TM - 1 - tau : tau;
      pendA = out + (((size_t)((1 + dir * 3) * BB + brow)) * TM + tout) * NU + ubase + cn;
      pendV = hv;
    }

    // ======== L1 PHASE ========
    // ---- h1 poll (tlay0's pend rides iter1 when it stored this tick)
    const unsigned int* c1a = Hbuf + ((size_t)((2 + p) * 8 + cluster)) * 4096 + tid * 8;
    const unsigned int* c1b = c1a + 4;
    u32x4 b0v = {0, 0, 0, 0}, b1v = {0, 0, 0, 0};
    {
      const bool st = (tlay == 0) && doL0;
      bool first = true;
      int miss = 0;
      for (;;) {
        LLC_LOAD16(b0v, c1a);
        LLC_LOAD16(b1v, c1b);
        if (first) {
          first = false;
          if (st) { STORE4(pendA, pendV); VMCNT(1); } else { VMCNT(0); }
        } else {
          VMCNT(0);
        }
        SCHEDBAR();
        if (__all(tags8(b0v, b1v, tg))) break;
        if (++miss > 2) __builtin_amdgcn_s_sleep(1);
      }
    }
    // stage h1
    u32x4 s1;
    s1[0] = (b0v[0] & 0xFFFFu) | (b0v[1] << 16);
    s1[1] = (b0v[2] & 0xFFFFu) | (b0v[3] << 16);
    s1[2] = (b1v[0] & 0xFFFFu) | (b1v[1] << 16);
    s1[3] = (b1v[2] & 0xFFFFu) | (b1v[3] << 16);
    *(u32x4*)(hlb1 + wsw) = s1;
    LGKM0(); SCHEDBAR(); BAR();

    // L1 MFMAs: W1 @ h0 (tile from L0 phase) + U1 @ h1
    #pragma unroll
    for (int kb = 0; kb < 4; kb++) {
      short8 h0f = *(const short8*)(hlb0 + ((fb + kb * 64 + q * 16) ^ fx));
      acc1 = __builtin_amdgcn_mfma_f32_16x16x32_bf16(h0f, wreg[8 + kb], acc1, 0, 0, 0);
      short8 h1f = *(const short8*)(hlb1 + ((fb + kb * 64 + q * 16) ^ fx));
      acc1 = __builtin_amdgcn_mfma_f32_16x16x32_bf16(h1f, wreg[12 + kb], acc1, 0, 0, 0);
    }
    #pragma unroll
    for (int j = 0; j < 4; j++) zpart[zwr + (((q << 2) + j) << 4)] = acc1[j];
    LGKM0(); SCHEDBAR(); BAR();

    // combine L1 (step tau-1) + ea refill + h1 ring store (tick end)
    if (tlay == 1) {
      float z[4];
      #pragma unroll
      for (int gg = 0; gg < 4; gg++)
        z[gg] = zpart[(gg * 2) * 256 + crow * 16 + cn] +
                zpart[(gg * 2 + 1) * 256 + crow * 16 + cn] + bi[gg];
      float cnw = sigm(z[1]) * cst + sigm(z[0]) * tanhp(z[2]);
      float hnw = sigm(z[3]) * tanhp(cnw);
      if (mskl[brow * 256 + (tau - 1)]) { cst = cnw; hv = hnw; }
    }
    if (tau < TM - 1) {  // ea refill for tick tau+1 (before h1 ring store)
      int tx1 = dir ? TM - (tau + 1) : (tau + 1);
      const unsigned short* e1 =
          embb + ((size_t)((rg * 16 + n15) * TT + tx1)) * NU + kh * 128 + q * 8;
      #pragma unroll
      for (int kb = 0; kb < 4; kb++) CACH_LOAD16(ea[kb], e1 + kb * 32);
    }
    SCHEDBAR();
    if (tlay == 1) {
      __hip_atomic_store(hst + (size_t)(tau & 1) * 32768,
                         ((unsigned)(tau + 1) << 16) | (unsigned)f2bf(hv),
                         __ATOMIC_RELAXED, __HIP_MEMORY_SCOPE_AGENT);
      int tout = dir ? TM - 1 - (tau - 1) : (tau - 1);
      pendA = out + (((size_t)((2 + dir * 3) * BB + brow)) * TM + tout) * NU + ubase + cn;
      pendV = hv;
    }
  }

  // flush tlay1's final pend (L1 step 254 out)
  if (tlay == 1) STORE4(pendA, pendV);
}

extern "C" void kernel_launch(void* const* d_in, const int* in_sizes, int n_in,
                              void* d_out, int out_size, void* d_ws, size_t ws_size,
                              hipStream_t stream) {
  const int* seqs = (const int*)d_in[0];
  const float* E = (const float*)d_in[1];
  const float* Wf = (const float*)d_in[2];
  const float* Uf = (const float*)d_in[3];
  const float* bfp = (const float*)d_in[4];
  const float* Wb = (const float*)d_in[5];
  const float* Ub = (const float*)d_in[6];
  const float* bbp = (const float*)d_in[7];
  float* out = (float*)d_out;

  char* ws = (char*)d_ws;
  unsigned int* Hbuf = (unsigned int*)ws;                 // 512KB ring + 256KB dump
  unsigned short* embb = (unsigned short*)(ws + 1048576); // 8MB bf16 emb

  hipMemsetAsync(Hbuf, 0, 4 * 8 * 4096 * sizeof(unsigned int), stream);

  hipLaunchKernelGGL(embed_kernel, dim3(BB, TT), dim3(256), 0, stream,
                     seqs, E, embb, out);

  int smem = 40960;  // 8K zpart + 2x8K h tiles + 16K mask
  hipFuncSetAttribute(reinterpret_cast<const void*>(lstm_kernel),
                      hipFuncAttributeMaxDynamicSharedMemorySize, smem);
  hipLaunchKernelGGL(lstm_kernel, dim3(128), dim3(512), smem, stream,
                     seqs, Wf, Uf, bfp, Wb, Ub, bbp, embb, Hbuf, out);
}